// Round 18
// baseline (193.276 us; speedup 1.0000x reference)
//
#include <hip/hip_runtime.h>
#include <hip/hip_bf16.h>

// Three-phase scheme (semantics = R9-certified HD ordering):
//   PASS 0 (fused): X -> A2 [M][2K] bf16 Dekker planes; W -> BT [N][K] bf16
//            sign transposed; flag counter reset.
//   PASS 1:  bulk GEMM 256x256, BK=64 virtual-k tiles, 2x64KB LDS dbuf,
//            m201-style 4-phase interleave per tile:
//              phase(ks,ch): ds_read(A 8 if ch==0; B 2) -> barrier ->
//              lgkmcnt(0)+sched_barrier(0) -> setprio(1) 16 MFMA setprio(0)
//              -> barrier.
//            Tile top: STAGE(t+1) -> other buffer, vmcnt(8) retires L(t),
//            barrier certifies buffer ready. Race ledger: each phase's
//            ds_reads drain (lgkmcnt 0) before its closing barrier, so a
//            buffer's readers are provably done >=2 barriers before re-stage.
//            128B-row XOR-swizzled LDS (R14-proven, 0 bank conflicts).
//            Writes sign(D); flags |D| < TAU (=6e-3 >> 20sigma bulk err).
//   PASS 2:  wave-cooperative exact fixup (BT gather + 6-lane HD panels
//            [384x5,128] folded left-to-right, bit-identical chain).
// Fallback (small ws / odd shapes): R12-certified fused bulk + W-col fixup.

typedef __bf16 bf16x8 __attribute__((ext_vector_type(8)));
typedef float f32x4 __attribute__((ext_vector_type(4)));

#define TAU 6e-3f

__device__ __forceinline__ float sgnf(float v) {
    return (v > 0.f) ? 1.f : ((v < 0.f) ? -1.f : 0.f);
}
__device__ __forceinline__ ushort f2bf(float x) {            // f32->bf16 RNE
    uint u = __float_as_uint(x);
    u += 0x7FFFu + ((u >> 16) & 1u);
    return (ushort)(u >> 16);
}
__device__ __forceinline__ float bf2f(ushort h) {
    return __uint_as_float(((uint)h) << 16);
}
__device__ __forceinline__ ushort sgnbf(float w) {           // sign as bf16
    return (w > 0.f) ? (ushort)0x3F80 : ((w < 0.f) ? (ushort)0xBF80 : (ushort)0);
}

// ---------------- PASS 0: fused pre-pass (conv rows + transpose tiles) -----
__global__ __launch_bounds__(256)
void pre_pass(const float* __restrict__ X, const float* __restrict__ W,
              ushort* __restrict__ A2, ushort* __restrict__ BT,
              uint* __restrict__ flags, int M, int K, int N)
{
    __shared__ float tile[64][65];
    const int b = blockIdx.x;

    if (b == 0 && threadIdx.x == 0) flags[0] = 0u;

    if (b < M) {
        const int m  = b;
        const int j8 = threadIdx.x * 8;
        if (j8 >= K) return;

        const float4 v0 = *(const float4*)&X[(size_t)m * K + j8];
        const float4 v1 = *(const float4*)&X[(size_t)m * K + j8 + 4];
        const float xs[8] = {v0.x, v0.y, v0.z, v0.w, v1.x, v1.y, v1.z, v1.w};

        ushort h1[8], h2[8];
        #pragma unroll
        for (int e = 0; e < 8; ++e) {
            h1[e] = f2bf(xs[e]);
            h2[e] = f2bf(xs[e] - bf2f(h1[e]));   // exact residual
        }
        uint4 p1, p2;
        p1.x = (uint)h1[0] | ((uint)h1[1] << 16);
        p1.y = (uint)h1[2] | ((uint)h1[3] << 16);
        p1.z = (uint)h1[4] | ((uint)h1[5] << 16);
        p1.w = (uint)h1[6] | ((uint)h1[7] << 16);
        p2.x = (uint)h2[0] | ((uint)h2[1] << 16);
        p2.y = (uint)h2[2] | ((uint)h2[3] << 16);
        p2.z = (uint)h2[4] | ((uint)h2[5] << 16);
        p2.w = (uint)h2[6] | ((uint)h2[7] << 16);

        ushort* row = A2 + (size_t)m * 2 * K;
        *(uint4*)(row + j8)     = p1;
        *(uint4*)(row + K + j8) = p2;
    } else {
        const int tb  = b - M;
        const int nbx = N >> 6;
        const int k0  = (tb / nbx) * 64;
        const int n0  = (tb % nbx) * 64;
        const int tr  = threadIdx.x >> 6;
        const int tc  = threadIdx.x & 63;

        #pragma unroll
        for (int h = 0; h < 16; ++h) {
            const int r = h * 4 + tr;
            tile[r][tc] = W[(size_t)(k0 + r) * N + n0 + tc];
        }
        __syncthreads();

        const int nr = threadIdx.x >> 2;
        const int kc = (threadIdx.x & 3) * 16;
        ushort sb[16];
        #pragma unroll
        for (int e = 0; e < 16; ++e) sb[e] = sgnbf(tile[kc + e][nr]);

        uint4 a2, b2;
        a2.x = (uint)sb[0]  | ((uint)sb[1]  << 16);
        a2.y = (uint)sb[2]  | ((uint)sb[3]  << 16);
        a2.z = (uint)sb[4]  | ((uint)sb[5]  << 16);
        a2.w = (uint)sb[6]  | ((uint)sb[7]  << 16);
        b2.x = (uint)sb[8]  | ((uint)sb[9]  << 16);
        b2.y = (uint)sb[10] | ((uint)sb[11] << 16);
        b2.z = (uint)sb[12] | ((uint)sb[13] << 16);
        b2.w = (uint)sb[14] | ((uint)sb[15] << 16);

        ushort* dst = BT + (size_t)(n0 + nr) * K + k0 + kc;
        *(uint4*)dst       = a2;
        *(uint4*)(dst + 8) = b2;
    }
}

// ---------------- PASS 1: BK=64 dbuf, 4-phase interleave per tile ----------
__global__ __launch_bounds__(512, 1)
void bulk_mfma_8p(const ushort* __restrict__ A2,   // [M][2K] bf16
                  const ushort* __restrict__ BT,   // [N][K]  bf16
                  float* __restrict__ O,
                  uint* __restrict__ flags, uint cap,
                  int M, int N, int K)
{
    __shared__ __align__(16) char lds[131072];  // 2 bufs x {A 32KB | B 32KB}

    const int tid = threadIdx.x;
    const int l   = tid & 63;
    const int wid = tid >> 6;          // 0..7
    const int wm  = wid >> 2;          // 0..1
    const int wn  = wid & 3;           // 0..3
    const int lr  = l & 15;
    const int lk  = l >> 4;

    // bijective XCD swizzle (nwg % 8 == 0)
    const int nwg = gridDim.x;
    int wg = blockIdx.x;
    wg = (wg & 7) * (nwg >> 3) + (wg >> 3);
    const int nbx = N >> 8;
    const int m0 = (wg / nbx) << 8;
    const int n0 = (wg % nbx) << 8;

    const int NTv = (2 * K) >> 6;              // 64 virtual-64k tiles
    const int NTr = K >> 6;                    // 32 real tiles (B wraps)
    const size_t rowA = (size_t)(2 * K) * 2;   // bytes per A2 row
    const size_t rowB = (size_t)K * 2;
    const char* A2b = (const char*)A2;
    const char* BTb = (const char*)BT;

    f32x4 acc[8][4];
    #pragma unroll
    for (int i = 0; i < 8; ++i)
        #pragma unroll
        for (int j = 0; j < 4; ++j)
            acc[i][j] = (f32x4){0.f, 0.f, 0.f, 0.f};

    // Stage tile t into buffer buf: 8 gload_lds/thread (4 A + 4 B chunks).
    // A: 256 rows x 128B (32 chunks of 8 rows), B same. Inverse swizzle on
    // the per-lane SOURCE byte; linear wave-uniform LDS dest (rule #21).
    const int lrow = l >> 3;
    const int bs   = (((l & 7) ^ lrow) << 4);
    auto STAGE = [&](int buf, int t) {
        char* base = lds + buf * 65536;
        const size_t kA = (size_t)t << 7;                    // t*128 bytes
        const size_t kB = (size_t)(t & (NTr - 1)) << 7;      // wraps per plane
        #pragma unroll
        for (int h = 0; h < 4; ++h) {
            const int c   = wid * 4 + h;          // chunk 0..31
            const int row = c * 8 + lrow;         // 0..255
            const char* srcA = A2b + (size_t)(m0 + row) * rowA + kA + bs;
            __builtin_amdgcn_global_load_lds(
                (const __attribute__((address_space(1))) void*)srcA,
                (__attribute__((address_space(3))) void*)(base + c * 1024),
                16, 0, 0);
            const char* srcB = BTb + (size_t)(n0 + row) * rowB + kB + bs;
            __builtin_amdgcn_global_load_lds(
                (const __attribute__((address_space(1))) void*)srcB,
                (__attribute__((address_space(3))) void*)(base + 32768 + c * 1024),
                16, 0, 0);
        }
    };

    // prologue: tile 0 in flight (8 loads/wave)
    STAGE(0, 0);

    for (int t = 0; t < NTv; ++t) {
        const char* sA = lds + (t & 1) * 65536;
        const char* sB = sA + 32768;

        // stage t+1 into the other buffer (its readers drained at end of
        // tile t-1, >=2 barriers ago); then retire exactly L(t) (8 oldest).
        if (t + 1 < NTv) {
            STAGE((t + 1) & 1, t + 1);
            asm volatile("s_waitcnt vmcnt(8)" ::: "memory");
        } else {
            asm volatile("s_waitcnt vmcnt(0)" ::: "memory");
        }
        __builtin_amdgcn_s_barrier();   // all waves certified: buf(t&1) ready

        bf16x8 af[8], bg[2];
        #pragma unroll
        for (int ks = 0; ks < 2; ++ks) {
            // A-frags for this kstep (read once, reused across col-halves)
            #pragma unroll
            for (int i = 0; i < 8; ++i) {
                const int r = wm * 128 + i * 16 + lr;
                af[i] = *(const bf16x8*)(sA + r * 128 +
                        ((ks * 64 + lk * 16) ^ ((r & 7) << 4)));
            }
            #pragma unroll
            for (int ch = 0; ch < 2; ++ch) {
                // B-frags for this col-half
                #pragma unroll
                for (int jj = 0; jj < 2; ++jj) {
                    const int r = wn * 64 + (2 * ch + jj) * 16 + lr;
                    bg[jj] = *(const bf16x8*)(sB + r * 128 +
                             ((ks * 64 + lk * 16) ^ ((r & 7) << 4)));
                }
                __builtin_amdgcn_s_barrier();                   // phase align
                asm volatile("s_waitcnt lgkmcnt(0)" ::: "memory");
                __builtin_amdgcn_sched_barrier(0);              // rule #18
                __builtin_amdgcn_s_setprio(1);
                #pragma unroll
                for (int i = 0; i < 8; ++i)
                    #pragma unroll
                    for (int jj = 0; jj < 2; ++jj)
                        acc[i][2 * ch + jj] =
                            __builtin_amdgcn_mfma_f32_16x16x32_bf16(
                                af[i], bg[jj], acc[i][2 * ch + jj], 0, 0, 0);
                __builtin_amdgcn_s_setprio(0);
                __builtin_amdgcn_s_barrier();                   // phase close
            }
        }
    }

    // epilogue: sign + borderline flagging (C/D: col=lane&15, row=lk*4+q)
    #pragma unroll
    for (int i = 0; i < 8; ++i) {
        #pragma unroll
        for (int j = 0; j < 4; ++j) {
            #pragma unroll
            for (int q = 0; q < 4; ++q) {
                const int m = m0 + wm * 128 + i * 16 + lk * 4 + q;
                const int n = n0 + wn * 64 + j * 16 + lr;
                const float d = acc[i][j][q];
                const size_t oi = (size_t)m * N + n;
                O[oi] = sgnf(d);
                if (fabsf(d) < TAU) {
                    const uint pos = atomicAdd(flags, 1u);
                    if (pos < cap) flags[1 + pos] = (uint)oi;
                }
            }
        }
    }
}

// ---------------- FALLBACK bulk (R12-certified, fused conversion) ----------
__global__ __launch_bounds__(256, 2)
void bulk_mfma_fb(const float* __restrict__ X, const float* __restrict__ W,
                  float* __restrict__ O, uint* __restrict__ flags,
                  uint cap, int M, int N, int K)
{
    __shared__ __align__(16) char sA[128 * 128];
    __shared__ __align__(16) char sB[128 * 128];

    const int tid = threadIdx.x;
    const int l   = tid & 63;
    const int w   = tid >> 6;
    const int wr  = w >> 1, wc = w & 1;
    const int lr  = l & 15;
    const int lk  = l >> 4;

    const int m0 = blockIdx.y * 128;
    const int n0 = blockIdx.x * 128;

    f32x4 acc[4][4];
    #pragma unroll
    for (int i = 0; i < 4; ++i)
        #pragma unroll
        for (int j = 0; j < 4; ++j)
            acc[i][j] = (f32x4){0.f, 0.f, 0.f, 0.f};

    const int NT = K / 64;

    for (int kt = 0; kt < 2 * NT; ++kt) {
        const int plane = (kt >= NT);
        const int kr0 = (plane ? (kt - NT) : kt) * 64;

        #pragma unroll
        for (int h = 0; h < 4; ++h) {
            const int idx = tid + 256 * h;
            const int r   = idx >> 3;
            const int c8  = (idx & 7) * 8;
            const float* xp = &X[(size_t)(m0 + r) * K + kr0 + c8];
            const float4 v0 = *(const float4*)xp;
            const float4 v1 = *(const float4*)(xp + 4);
            const float xs[8] = {v0.x, v0.y, v0.z, v0.w, v1.x, v1.y, v1.z, v1.w};
            ushort hb[8];
            if (!plane) {
                #pragma unroll
                for (int e = 0; e < 8; ++e) hb[e] = f2bf(xs[e]);
            } else {
                #pragma unroll
                for (int e = 0; e < 8; ++e) {
                    const ushort h1 = f2bf(xs[e]);
                    hb[e] = f2bf(xs[e] - bf2f(h1));
                }
            }
            uint4 pk;
            pk.x = (uint)hb[0] | ((uint)hb[1] << 16);
            pk.y = (uint)hb[2] | ((uint)hb[3] << 16);
            pk.z = (uint)hb[4] | ((uint)hb[5] << 16);
            pk.w = (uint)hb[6] | ((uint)hb[7] << 16);
            *(uint4*)(sA + r * 128 + ((c8 * 2) ^ ((r & 7) << 4))) = pk;
        }
        {
            const int ko = (tid >> 5) * 8;
            const int n4 = (tid & 31) * 4;
            float4 rv[8];
            #pragma unroll
            for (int j = 0; j < 8; ++j)
                rv[j] = *(const float4*)&W[(size_t)(kr0 + ko + j) * N + n0 + n4];
            #pragma unroll
            for (int c = 0; c < 4; ++c) {
                ushort sb[8];
                #pragma unroll
                for (int j = 0; j < 8; ++j)
                    sb[j] = sgnbf(((const float*)&rv[j])[c]);
                uint4 pk;
                pk.x = (uint)sb[0] | ((uint)sb[1] << 16);
                pk.y = (uint)sb[2] | ((uint)sb[3] << 16);
                pk.z = (uint)sb[4] | ((uint)sb[5] << 16);
                pk.w = (uint)sb[6] | ((uint)sb[7] << 16);
                const int row = n4 + c;
                *(uint4*)(sB + row * 128 + ((ko * 2) ^ ((row & 7) << 4))) = pk;
            }
        }
        __syncthreads();

        #pragma unroll
        for (int kk = 0; kk < 2; ++kk) {
            const int kb = kk * 64 + lk * 16;
            bf16x8 af[4], bg[4];
            #pragma unroll
            for (int i = 0; i < 4; ++i) {
                const int row = wr * 64 + i * 16 + lr;
                af[i] = *(const bf16x8*)(sA + row * 128 + (kb ^ ((row & 7) << 4)));
            }
            #pragma unroll
            for (int j = 0; j < 4; ++j) {
                const int row = wc * 64 + j * 16 + lr;
                bg[j] = *(const bf16x8*)(sB + row * 128 + (kb ^ ((row & 7) << 4)));
            }
            #pragma unroll
            for (int i = 0; i < 4; ++i)
                #pragma unroll
                for (int j = 0; j < 4; ++j)
                    acc[i][j] = __builtin_amdgcn_mfma_f32_16x16x32_bf16(
                        af[i], bg[j], acc[i][j], 0, 0, 0);
        }
        __syncthreads();
    }

    #pragma unroll
    for (int i = 0; i < 4; ++i) {
        #pragma unroll
        for (int j = 0; j < 4; ++j) {
            #pragma unroll
            for (int q = 0; q < 4; ++q) {
                const int m = m0 + wr * 64 + i * 16 + lk * 4 + q;
                const int n = n0 + wc * 64 + j * 16 + lr;
                const float d = acc[i][j][q];
                const size_t oi = (size_t)m * N + n;
                O[oi] = sgnf(d);
                if (fabsf(d) < TAU) {
                    const uint pos = atomicAdd(flags, 1u);
                    if (pos < cap) flags[1 + pos] = (uint)oi;
                }
            }
        }
    }
}

// ---------------- PASS 2: fixup, BT gather + 6-lane panel-parallel chain ---
__global__ __launch_bounds__(64)
void fixup_exact_bt(const float* __restrict__ X, const ushort* __restrict__ BT,
                    float* __restrict__ O, const uint* __restrict__ flags,
                    uint cap, int K, int N)
{
    __shared__ float p[2048];

    uint count = flags[0];
    if (count > cap) count = cap;

    for (uint t = blockIdx.x; t < count; t += gridDim.x) {
        const uint idx = flags[1 + t];
        const int n = (int)(idx % (uint)N);
        const float* xrow = X + (size_t)(idx / (uint)N) * K;
        const ushort* brow = BT + (size_t)n * K;

        for (int k4 = threadIdx.x * 4; k4 < K; k4 += 256) {
            const float4 xv = *(const float4*)&xrow[k4];
            const ushort4 bv = *(const ushort4*)&brow[k4];
            float4 pr;
            pr.x = xv.x * bf2f(bv.x);
            pr.y = xv.y * bf2f(bv.y);
            pr.z = xv.z * bf2f(bv.z);
            pr.w = xv.w * bf2f(bv.w);
            *(float4*)&p[k4] = pr;       // exact +-x products
        }
        __syncthreads();

        // HD panels [384x5,128]: panel t on lane t (internally sequential),
        // folded left-to-right (exact order).
        float partial = 0.f;
        const int ls = (int)threadIdx.x * 384;
        if (ls < K) {
            const int ke = (ls + 384 < K) ? (ls + 384) : K;
            for (int k = ls; k < ke; ++k) partial += p[k];
        }
        float sum = 0.f;
        #pragma unroll
        for (int q = 0; q < 6; ++q) sum += __shfl(partial, q);
        if (threadIdx.x == 0) O[idx] = sgnf(sum);
        __syncthreads();
    }
}

// ---------------- fallback fixup (reads W columns) ----------------
__global__ __launch_bounds__(64)
void fixup_exact_wave(const float* __restrict__ X, const float* __restrict__ W,
                      float* __restrict__ O, const uint* __restrict__ flags,
                      uint cap, int K, int N)
{
    __shared__ float p[2048];

    uint count = flags[0];
    if (count > cap) count = cap;

    for (uint t = blockIdx.x; t < count; t += gridDim.x) {
        const uint idx = flags[1 + t];
        const int n = (int)(idx % (uint)N);
        const float* xrow = X + (size_t)(idx / (uint)N) * K;
        const float* wcol = W + n;

        if (K <= 2048) {
            for (int k = threadIdx.x; k < K; k += 64)
                p[k] = xrow[k] * sgnf(wcol[(size_t)k * N]);
            __syncthreads();
            if (threadIdx.x == 0) {
                float sum = 0.f;
                int ls = 0;
                while (ls < K) {
                    const int ke = (ls + 384 < K) ? (ls + 384) : K;
                    float part = 0.f;
                    for (int k = ls; k < ke; ++k) part += p[k];
                    sum += part;
                    ls = ke;
                }
                O[idx] = sgnf(sum);
            }
            __syncthreads();
        } else if (threadIdx.x == 0) {
            float sum = 0.f;
            int ls = 0;
            while (ls < K) {
                const int ke = (ls + 384 < K) ? (ls + 384) : K;
                float part = 0.f;
                for (int k = ls; k < ke; ++k)
                    part = fmaf(xrow[k], sgnf(wcol[(size_t)k * N]), part);
                sum += part;
                ls = ke;
            }
            O[idx] = sgnf(sum);
        }
    }
}

extern "C" void kernel_launch(void* const* d_in, const int* in_sizes, int n_in,
                              void* d_out, int out_size, void* d_ws, size_t ws_size,
                              hipStream_t stream) {
    // order-robust input binding (x = larger buffer)
    const float* X;
    const float* W;
    long long wsize;
    if ((long long)in_sizes[0] >= (long long)in_sizes[1]) {
        X = (const float*)d_in[0];
        W = (const float*)d_in[1]; wsize = in_sizes[1];
    } else {
        X = (const float*)d_in[1];
        W = (const float*)d_in[0]; wsize = in_sizes[0];
    }
    float* O = (float*)d_out;

    int K = 1;
    while ((long long)K * K < wsize) ++K;        // K = 2048
    const int N = K;
    const int M = (int)((long long)out_size / N);

    const size_t A2_BYTES = (size_t)M * 2 * K * 2;   // 64 MB
    const size_t BT_BYTES = (size_t)N * K * 2;       // 8 MB
    const size_t FLAG_OFF = A2_BYTES + BT_BYTES;
    const bool big_ws = (ws_size >= FLAG_OFF + (1u << 16)) &&
                        (M % 256 == 0) && (N % 256 == 0) &&
                        (K % 64 == 0) && (K >= 256) && (K <= 2048) &&
                        ((K & (K - 1)) == 0);        // NTr power of 2

    if (big_ws) {
        ushort* A2 = (ushort*)d_ws;
        ushort* BT = (ushort*)((char*)d_ws + A2_BYTES);
        uint* flags = (uint*)((char*)d_ws + FLAG_OFF);
        unsigned long long c = (unsigned long long)((ws_size - FLAG_OFF) / 4) - 1ull;
        const uint cap = (uint)((c > 0x00FFFFFFull) ? 0x00FFFFFFull : c);

        const int pre_grid = M + (N / 64) * (K / 64);
        pre_pass<<<pre_grid, 256, 0, stream>>>(X, W, A2, BT, flags, M, K, N);
        const int nwg = (N / 256) * (M / 256);       // 256, % 8 == 0
        bulk_mfma_8p<<<nwg, 512, 0, stream>>>(A2, BT, O, flags, cap, M, N, K);
        fixup_exact_bt<<<2048, 64, 0, stream>>>(X, BT, O, flags, cap, K, N);
    } else {
        uint* flags = (uint*)d_ws;
        uint cap = 0;
        if (ws_size >= 8) {
            unsigned long long c = (unsigned long long)(ws_size / 4) - 1ull;
            cap = (uint)((c > 0x00FFFFFFull) ? 0x00FFFFFFull : c);
        }
        hipMemsetAsync(d_ws, 0, 4, stream);
        dim3 grid(N / 128, M / 128);
        bulk_mfma_fb<<<grid, 256, 0, stream>>>(X, W, O, flags, cap, M, N, K);
        fixup_exact_wave<<<2048, 64, 0, stream>>>(X, W, O, flags, cap, K, N);
    }
}

// Round 19
// 186.027 us; speedup vs baseline: 1.0390x; 1.0390x over previous
//
#include <hip/hip_runtime.h>
#include <hip/hip_bf16.h>

// Three-phase scheme (semantics = R9-certified HD ordering):
//   PASS 0 (fused): X -> A2 [M][2K] bf16 Dekker planes; W -> BT [N][K] bf16
//            sign transposed; flag counter reset.
//   PASS 1:  bulk GEMM 256x128 tile, 8 waves of 64x64 (acc = 64 AGPR),
//            BK=32 virtual-k, 2 x 24KB LDS dbuf (48KB -> 2 BLOCKS/CU; the
//            R14-R18 plateau at ~139us was 1-block/CU lockstep: no cross-
//            block wave overlap, m114 mechanism). Counted vmcnt(3) retires
//            exactly subtile s (FIFO), 2 barriers/subtile (R14 skeleton).
//            Pair-row 128B XOR-swizzled LDS (R17-proven, 0 conflicts).
//            __launch_bounds__(512,4) caps combined regs at 128/thread so
//            two 8-wave blocks co-reside (4 waves/SIMD).
//            Writes sign(D); flags |D| < TAU (=6e-3 >> 20sigma bulk err).
//   PASS 2:  wave-cooperative exact fixup (BT gather + 6-lane HD panels
//            [384x5,128] folded left-to-right, bit-identical chain).
// Fallback (small ws / odd shapes): R12-certified fused bulk + W-col fixup.

typedef __bf16 bf16x8 __attribute__((ext_vector_type(8)));
typedef float f32x4 __attribute__((ext_vector_type(4)));

#define TAU 6e-3f

__device__ __forceinline__ float sgnf(float v) {
    return (v > 0.f) ? 1.f : ((v < 0.f) ? -1.f : 0.f);
}
__device__ __forceinline__ ushort f2bf(float x) {            // f32->bf16 RNE
    uint u = __float_as_uint(x);
    u += 0x7FFFu + ((u >> 16) & 1u);
    return (ushort)(u >> 16);
}
__device__ __forceinline__ float bf2f(ushort h) {
    return __uint_as_float(((uint)h) << 16);
}
__device__ __forceinline__ ushort sgnbf(float w) {           // sign as bf16
    return (w > 0.f) ? (ushort)0x3F80 : ((w < 0.f) ? (ushort)0xBF80 : (ushort)0);
}

// ---------------- PASS 0: fused pre-pass (conv rows + transpose tiles) -----
__global__ __launch_bounds__(256)
void pre_pass(const float* __restrict__ X, const float* __restrict__ W,
              ushort* __restrict__ A2, ushort* __restrict__ BT,
              uint* __restrict__ flags, int M, int K, int N)
{
    __shared__ float tile[64][65];
    const int b = blockIdx.x;

    if (b == 0 && threadIdx.x == 0) flags[0] = 0u;

    if (b < M) {
        const int m  = b;
        const int j8 = threadIdx.x * 8;
        if (j8 >= K) return;

        const float4 v0 = *(const float4*)&X[(size_t)m * K + j8];
        const float4 v1 = *(const float4*)&X[(size_t)m * K + j8 + 4];
        const float xs[8] = {v0.x, v0.y, v0.z, v0.w, v1.x, v1.y, v1.z, v1.w};

        ushort h1[8], h2[8];
        #pragma unroll
        for (int e = 0; e < 8; ++e) {
            h1[e] = f2bf(xs[e]);
            h2[e] = f2bf(xs[e] - bf2f(h1[e]));   // exact residual
        }
        uint4 p1, p2;
        p1.x = (uint)h1[0] | ((uint)h1[1] << 16);
        p1.y = (uint)h1[2] | ((uint)h1[3] << 16);
        p1.z = (uint)h1[4] | ((uint)h1[5] << 16);
        p1.w = (uint)h1[6] | ((uint)h1[7] << 16);
        p2.x = (uint)h2[0] | ((uint)h2[1] << 16);
        p2.y = (uint)h2[2] | ((uint)h2[3] << 16);
        p2.z = (uint)h2[4] | ((uint)h2[5] << 16);
        p2.w = (uint)h2[6] | ((uint)h2[7] << 16);

        ushort* row = A2 + (size_t)m * 2 * K;
        *(uint4*)(row + j8)     = p1;
        *(uint4*)(row + K + j8) = p2;
    } else {
        const int tb  = b - M;
        const int nbx = N >> 6;
        const int k0  = (tb / nbx) * 64;
        const int n0  = (tb % nbx) * 64;
        const int tr  = threadIdx.x >> 6;
        const int tc  = threadIdx.x & 63;

        #pragma unroll
        for (int h = 0; h < 16; ++h) {
            const int r = h * 4 + tr;
            tile[r][tc] = W[(size_t)(k0 + r) * N + n0 + tc];
        }
        __syncthreads();

        const int nr = threadIdx.x >> 2;
        const int kc = (threadIdx.x & 3) * 16;
        ushort sb[16];
        #pragma unroll
        for (int e = 0; e < 16; ++e) sb[e] = sgnbf(tile[kc + e][nr]);

        uint4 a2, b2;
        a2.x = (uint)sb[0]  | ((uint)sb[1]  << 16);
        a2.y = (uint)sb[2]  | ((uint)sb[3]  << 16);
        a2.z = (uint)sb[4]  | ((uint)sb[5]  << 16);
        a2.w = (uint)sb[6]  | ((uint)sb[7]  << 16);
        b2.x = (uint)sb[8]  | ((uint)sb[9]  << 16);
        b2.y = (uint)sb[10] | ((uint)sb[11] << 16);
        b2.z = (uint)sb[12] | ((uint)sb[13] << 16);
        b2.w = (uint)sb[14] | ((uint)sb[15] << 16);

        ushort* dst = BT + (size_t)(n0 + nr) * K + k0 + kc;
        *(uint4*)dst       = a2;
        *(uint4*)(dst + 8) = b2;
    }
}

// ---------------- PASS 1: 256x128 tile, 2 blocks/CU, BK=32, dbuf ----------
__global__ __launch_bounds__(512, 4)
void bulk_mfma_2blk(const ushort* __restrict__ A2,   // [M][2K] bf16
                    const ushort* __restrict__ BT,   // [N][K]  bf16
                    float* __restrict__ O,
                    uint* __restrict__ flags, uint cap,
                    int M, int N, int K)
{
    __shared__ __align__(16) char lds[49152];  // 2 bufs x {A 16K | B 8K}

    const int tid = threadIdx.x;
    const int l   = tid & 63;
    const int wid = tid >> 6;          // 0..7
    const int wm  = wid >> 1;          // 0..3 (M wave, 64 rows each)
    const int wn  = wid & 1;           // 0..1 (N wave, 64 cols each)
    const int lr  = l & 15;
    const int lk  = l >> 4;

    // bijective XCD swizzle (nwg % 8 == 0)
    const int nwg = gridDim.x;
    int wg = blockIdx.x;
    wg = (wg & 7) * (nwg >> 3) + (wg >> 3);
    const int nbx = N >> 7;            // N/128
    const int m0 = (wg / nbx) << 8;    // 256-row tiles
    const int n0 = (wg % nbx) << 7;    // 128-col tiles

    const int NSv = (2 * K) >> 5;              // 128 virtual-32k subtiles
    const int NSr = K >> 5;                    // 64 (B wraps per plane)
    const size_t rowA = (size_t)(2 * K) * 2;   // bytes per A2 row
    const size_t rowB = (size_t)K * 2;
    const char* A2b = (const char*)A2;
    const char* BTb = (const char*)BT;

    // staging lane math (R17-proven involution):
    const int u    = (l & 7) ^ (l >> 3);
    const int bit  = u >> 2;              // row parity within pair
    const int kloc = (u & 3) << 4;        // byte 0..48 within 64B k-chunk
    const int lrow = l >> 3;              // pair-row within chunk

    f32x4 acc[4][4];
    #pragma unroll
    for (int i = 0; i < 4; ++i)
        #pragma unroll
        for (int j = 0; j < 4; ++j)
            acc[i][j] = (f32x4){0.f, 0.f, 0.f, 0.f};

    // Stage subtile s into buffer buf: 3 gload_lds/thread (A 2 + B 1).
    // LDS A: 128 pair-rows x 128B (16 chunks of 1KB); B: 64 pair-rows (8 ch).
    auto STAGE = [&](int buf, int s) {
        char* base = lds + buf * 24576;
        const size_t kA = (size_t)s << 6;                  // byte col in A2
        const size_t kB = (size_t)(s & (NSr - 1)) << 6;    // wraps per plane
        #pragma unroll
        for (int h = 0; h < 2; ++h) {
            const int c = wid * 2 + h;                     // A chunk 0..15
            const int P = c * 8 + lrow;                    // pair-row 0..127
            const char* srcA = A2b + (size_t)(m0 + 2 * P + bit) * rowA + kA + kloc;
            __builtin_amdgcn_global_load_lds(
                (const __attribute__((address_space(1))) void*)srcA,
                (__attribute__((address_space(3))) void*)(base + c * 1024),
                16, 0, 0);
        }
        {
            const int c = wid;                             // B chunk 0..7
            const int P = c * 8 + lrow;                    // pair-row 0..63
            const char* srcB = BTb + (size_t)(n0 + 2 * P + bit) * rowB + kB + kloc;
            __builtin_amdgcn_global_load_lds(
                (const __attribute__((address_space(1))) void*)srcB,
                (__attribute__((address_space(3))) void*)(base + 16384 + c * 1024),
                16, 0, 0);
        }
    };

    // Compute subtile: 8 ds_read_b128 + 16 MFMA per wave.
    auto COMPUTE = [&](int buf) {
        const char* sA = lds + buf * 24576;
        const char* sB = sA + 16384;
        bf16x8 bg[4];
        #pragma unroll
        for (int j = 0; j < 4; ++j) {
            const int r = wn * 64 + j * 16 + lr;
            const int p = r >> 1;
            const int byt = (((r & 1) << 6) | (lk << 4)) ^ ((p & 7) << 4);
            bg[j] = *(const bf16x8*)(sB + p * 128 + byt);
        }
        bf16x8 af[4];
        #pragma unroll
        for (int i = 0; i < 4; ++i) {
            const int r = wm * 64 + i * 16 + lr;
            const int p = r >> 1;
            const int byt = (((r & 1) << 6) | (lk << 4)) ^ ((p & 7) << 4);
            af[i] = *(const bf16x8*)(sA + p * 128 + byt);
        }
        __builtin_amdgcn_s_setprio(1);
        #pragma unroll
        for (int i = 0; i < 4; ++i)
            #pragma unroll
            for (int j = 0; j < 4; ++j)
                acc[i][j] = __builtin_amdgcn_mfma_f32_16x16x32_bf16(
                    af[i], bg[j], acc[i][j], 0, 0, 0);
        __builtin_amdgcn_s_setprio(0);
    };

    // prologue: subtile 0 in flight (3 loads/thread)
    STAGE(0, 0);

    for (int s = 0; s < NSv; ++s) {
        // stage s+1 into the other buffer, then retire exactly s's 3 loads
        if (s + 1 < NSv) {
            STAGE((s + 1) & 1, s + 1);
            asm volatile("s_waitcnt vmcnt(3)" ::: "memory");
        } else {
            asm volatile("s_waitcnt vmcnt(0)" ::: "memory");
        }
        __builtin_amdgcn_s_barrier();          // buf(s&1) globally ready
        __builtin_amdgcn_sched_barrier(0);
        COMPUTE(s & 1);
        __builtin_amdgcn_s_barrier();          // all waves done reading buf
        __builtin_amdgcn_sched_barrier(0);
    }

    // epilogue: sign + borderline flagging (C/D: col=lane&15, row=lk*4+q)
    #pragma unroll
    for (int i = 0; i < 4; ++i) {
        #pragma unroll
        for (int j = 0; j < 4; ++j) {
            #pragma unroll
            for (int q = 0; q < 4; ++q) {
                const int m = m0 + wm * 64 + i * 16 + lk * 4 + q;
                const int n = n0 + wn * 64 + j * 16 + lr;
                const float d = acc[i][j][q];
                const size_t oi = (size_t)m * N + n;
                O[oi] = sgnf(d);
                if (fabsf(d) < TAU) {
                    const uint pos = atomicAdd(flags, 1u);
                    if (pos < cap) flags[1 + pos] = (uint)oi;
                }
            }
        }
    }
}

// ---------------- FALLBACK bulk (R12-certified, fused conversion) ----------
__global__ __launch_bounds__(256, 2)
void bulk_mfma_fb(const float* __restrict__ X, const float* __restrict__ W,
                  float* __restrict__ O, uint* __restrict__ flags,
                  uint cap, int M, int N, int K)
{
    __shared__ __align__(16) char sA[128 * 128];
    __shared__ __align__(16) char sB[128 * 128];

    const int tid = threadIdx.x;
    const int l   = tid & 63;
    const int w   = tid >> 6;
    const int wr  = w >> 1, wc = w & 1;
    const int lr  = l & 15;
    const int lk  = l >> 4;

    const int m0 = blockIdx.y * 128;
    const int n0 = blockIdx.x * 128;

    f32x4 acc[4][4];
    #pragma unroll
    for (int i = 0; i < 4; ++i)
        #pragma unroll
        for (int j = 0; j < 4; ++j)
            acc[i][j] = (f32x4){0.f, 0.f, 0.f, 0.f};

    const int NT = K / 64;

    for (int kt = 0; kt < 2 * NT; ++kt) {
        const int plane = (kt >= NT);
        const int kr0 = (plane ? (kt - NT) : kt) * 64;

        #pragma unroll
        for (int h = 0; h < 4; ++h) {
            const int idx = tid + 256 * h;
            const int r   = idx >> 3;
            const int c8  = (idx & 7) * 8;
            const float* xp = &X[(size_t)(m0 + r) * K + kr0 + c8];
            const float4 v0 = *(const float4*)xp;
            const float4 v1 = *(const float4*)(xp + 4);
            const float xs[8] = {v0.x, v0.y, v0.z, v0.w, v1.x, v1.y, v1.z, v1.w};
            ushort hb[8];
            if (!plane) {
                #pragma unroll
                for (int e = 0; e < 8; ++e) hb[e] = f2bf(xs[e]);
            } else {
                #pragma unroll
                for (int e = 0; e < 8; ++e) {
                    const ushort h1 = f2bf(xs[e]);
                    hb[e] = f2bf(xs[e] - bf2f(h1));
                }
            }
            uint4 pk;
            pk.x = (uint)hb[0] | ((uint)hb[1] << 16);
            pk.y = (uint)hb[2] | ((uint)hb[3] << 16);
            pk.z = (uint)hb[4] | ((uint)hb[5] << 16);
            pk.w = (uint)hb[6] | ((uint)hb[7] << 16);
            *(uint4*)(sA + r * 128 + ((c8 * 2) ^ ((r & 7) << 4))) = pk;
        }
        {
            const int ko = (tid >> 5) * 8;
            const int n4 = (tid & 31) * 4;
            float4 rv[8];
            #pragma unroll
            for (int j = 0; j < 8; ++j)
                rv[j] = *(const float4*)&W[(size_t)(kr0 + ko + j) * N + n0 + n4];
            #pragma unroll
            for (int c = 0; c < 4; ++c) {
                ushort sb[8];
                #pragma unroll
                for (int j = 0; j < 8; ++j)
                    sb[j] = sgnbf(((const float*)&rv[j])[c]);
                uint4 pk;
                pk.x = (uint)sb[0] | ((uint)sb[1] << 16);
                pk.y = (uint)sb[2] | ((uint)sb[3] << 16);
                pk.z = (uint)sb[4] | ((uint)sb[5] << 16);
                pk.w = (uint)sb[6] | ((uint)sb[7] << 16);
                const int row = n4 + c;
                *(uint4*)(sB + row * 128 + ((ko * 2) ^ ((row & 7) << 4))) = pk;
            }
        }
        __syncthreads();

        #pragma unroll
        for (int kk = 0; kk < 2; ++kk) {
            const int kb = kk * 64 + lk * 16;
            bf16x8 af[4], bg[4];
            #pragma unroll
            for (int i = 0; i < 4; ++i) {
                const int row = wr * 64 + i * 16 + lr;
                af[i] = *(const bf16x8*)(sA + row * 128 + (kb ^ ((row & 7) << 4)));
            }
            #pragma unroll
            for (int j = 0; j < 4; ++j) {
                const int row = wc * 64 + j * 16 + lr;
                bg[j] = *(const bf16x8*)(sB + row * 128 + (kb ^ ((row & 7) << 4)));
            }
            #pragma unroll
            for (int i = 0; i < 4; ++i)
                #pragma unroll
                for (int j = 0; j < 4; ++j)
                    acc[i][j] = __builtin_amdgcn_mfma_f32_16x16x32_bf16(
                        af[i], bg[j], acc[i][j], 0, 0, 0);
        }
        __syncthreads();
    }

    #pragma unroll
    for (int i = 0; i < 4; ++i) {
        #pragma unroll
        for (int j = 0; j < 4; ++j) {
            #pragma unroll
            for (int q = 0; q < 4; ++q) {
                const int m = m0 + wr * 64 + i * 16 + lk * 4 + q;
                const int n = n0 + wc * 64 + j * 16 + lr;
                const float d = acc[i][j][q];
                const size_t oi = (size_t)m * N + n;
                O[oi] = sgnf(d);
                if (fabsf(d) < TAU) {
                    const uint pos = atomicAdd(flags, 1u);
                    if (pos < cap) flags[1 + pos] = (uint)oi;
                }
            }
        }
    }
}

// ---------------- PASS 2: fixup, BT gather + 6-lane panel-parallel chain ---
__global__ __launch_bounds__(64)
void fixup_exact_bt(const float* __restrict__ X, const ushort* __restrict__ BT,
                    float* __restrict__ O, const uint* __restrict__ flags,
                    uint cap, int K, int N)
{
    __shared__ float p[2048];

    uint count = flags[0];
    if (count > cap) count = cap;

    for (uint t = blockIdx.x; t < count; t += gridDim.x) {
        const uint idx = flags[1 + t];
        const int n = (int)(idx % (uint)N);
        const float* xrow = X + (size_t)(idx / (uint)N) * K;
        const ushort* brow = BT + (size_t)n * K;

        for (int k4 = threadIdx.x * 4; k4 < K; k4 += 256) {
            const float4 xv = *(const float4*)&xrow[k4];
            const ushort4 bv = *(const ushort4*)&brow[k4];
            float4 pr;
            pr.x = xv.x * bf2f(bv.x);
            pr.y = xv.y * bf2f(bv.y);
            pr.z = xv.z * bf2f(bv.z);
            pr.w = xv.w * bf2f(bv.w);
            *(float4*)&p[k4] = pr;       // exact +-x products
        }
        __syncthreads();

        // HD panels [384x5,128]: panel t on lane t (internally sequential),
        // folded left-to-right (exact order).
        float partial = 0.f;
        const int ls = (int)threadIdx.x * 384;
        if (ls < K) {
            const int ke = (ls + 384 < K) ? (ls + 384) : K;
            for (int k = ls; k < ke; ++k) partial += p[k];
        }
        float sum = 0.f;
        #pragma unroll
        for (int q = 0; q < 6; ++q) sum += __shfl(partial, q);
        if (threadIdx.x == 0) O[idx] = sgnf(sum);
        __syncthreads();
    }
}

// ---------------- fallback fixup (reads W columns) ----------------
__global__ __launch_bounds__(64)
void fixup_exact_wave(const float* __restrict__ X, const float* __restrict__ W,
                      float* __restrict__ O, const uint* __restrict__ flags,
                      uint cap, int K, int N)
{
    __shared__ float p[2048];

    uint count = flags[0];
    if (count > cap) count = cap;

    for (uint t = blockIdx.x; t < count; t += gridDim.x) {
        const uint idx = flags[1 + t];
        const int n = (int)(idx % (uint)N);
        const float* xrow = X + (size_t)(idx / (uint)N) * K;
        const float* wcol = W + n;

        if (K <= 2048) {
            for (int k = threadIdx.x; k < K; k += 64)
                p[k] = xrow[k] * sgnf(wcol[(size_t)k * N]);
            __syncthreads();
            if (threadIdx.x == 0) {
                float sum = 0.f;
                int ls = 0;
                while (ls < K) {
                    const int ke = (ls + 384 < K) ? (ls + 384) : K;
                    float part = 0.f;
                    for (int k = ls; k < ke; ++k) part += p[k];
                    sum += part;
                    ls = ke;
                }
                O[idx] = sgnf(sum);
            }
            __syncthreads();
        } else if (threadIdx.x == 0) {
            float sum = 0.f;
            int ls = 0;
            while (ls < K) {
                const int ke = (ls + 384 < K) ? (ls + 384) : K;
                float part = 0.f;
                for (int k = ls; k < ke; ++k)
                    part = fmaf(xrow[k], sgnf(wcol[(size_t)k * N]), part);
                sum += part;
                ls = ke;
            }
            O[idx] = sgnf(sum);
        }
    }
}

extern "C" void kernel_launch(void* const* d_in, const int* in_sizes, int n_in,
                              void* d_out, int out_size, void* d_ws, size_t ws_size,
                              hipStream_t stream) {
    // order-robust input binding (x = larger buffer)
    const float* X;
    const float* W;
    long long wsize;
    if ((long long)in_sizes[0] >= (long long)in_sizes[1]) {
        X = (const float*)d_in[0];
        W = (const float*)d_in[1]; wsize = in_sizes[1];
    } else {
        X = (const float*)d_in[1];
        W = (const float*)d_in[0]; wsize = in_sizes[0];
    }
    float* O = (float*)d_out;

    int K = 1;
    while ((long long)K * K < wsize) ++K;        // K = 2048
    const int N = K;
    const int M = (int)((long long)out_size / N);

    const size_t A2_BYTES = (size_t)M * 2 * K * 2;   // 64 MB
    const size_t BT_BYTES = (size_t)N * K * 2;       // 8 MB
    const size_t FLAG_OFF = A2_BYTES + BT_BYTES;
    const bool big_ws = (ws_size >= FLAG_OFF + (1u << 16)) &&
                        (M % 256 == 0) && (N % 128 == 0) &&
                        (K % 64 == 0) && (K >= 256) && (K <= 2048) &&
                        ((K & (K - 1)) == 0);        // NSr power of 2

    if (big_ws) {
        ushort* A2 = (ushort*)d_ws;
        ushort* BT = (ushort*)((char*)d_ws + A2_BYTES);
        uint* flags = (uint*)((char*)d_ws + FLAG_OFF);
        unsigned long long c = (unsigned long long)((ws_size - FLAG_OFF) / 4) - 1ull;
        const uint cap = (uint)((c > 0x00FFFFFFull) ? 0x00FFFFFFull : c);

        const int pre_grid = M + (N / 64) * (K / 64);
        pre_pass<<<pre_grid, 256, 0, stream>>>(X, W, A2, BT, flags, M, K, N);
        const int nwg = (M / 256) * (N / 128);       // 512, % 8 == 0
        bulk_mfma_2blk<<<nwg, 512, 0, stream>>>(A2, BT, O, flags, cap, M, N, K);
        fixup_exact_bt<<<2048, 64, 0, stream>>>(X, BT, O, flags, cap, K, N);
    } else {
        uint* flags = (uint*)d_ws;
        uint cap = 0;
        if (ws_size >= 8) {
            unsigned long long c = (unsigned long long)(ws_size / 4) - 1ull;
            cap = (uint)((c > 0x00FFFFFFull) ? 0x00FFFFFFull : c);
        }
        hipMemsetAsync(d_ws, 0, 4, stream);
        dim3 grid(N / 128, M / 128);
        bulk_mfma_fb<<<grid, 256, 0, stream>>>(X, W, O, flags, cap, M, N, K);
        fixup_exact_wave<<<2048, 64, 0, stream>>>(X, W, O, flags, cap, K, N);
    }
}

// Round 20
// 167.605 us; speedup vs baseline: 1.1532x; 1.1099x over previous
//
#include <hip/hip_runtime.h>
#include <hip/hip_bf16.h>

// Three-phase scheme (semantics = R9-certified HD ordering):
//   PASS 0 (fused): X -> A2 [M][2K] bf16 Dekker planes; W -> BT [N][K] bf16
//            sign transposed; flag counter reset.
//   PASS 1:  bulk GEMM 256x256, BK=32 real-k, plane-shared B, 3 buffers,
//            counted vmcnt(12/6/0), 2 barriers/subtile (R16 skeleton,
//            138.8us, 0 bank conflicts). THIS ROUND: COMPUTE issues ALL 20
//            ds_reads (bg[4], af1[8], af2[8]) BEFORE the 64 MFMAs so the
//            compiler's counted lgkmcnt lets plane-2 reads fly under
//            plane-1 MFMAs (within-wave LDS/MFMA overlap).
//            Writes sign(D); flags |D| < TAU (=3e-3, >=9 sigma margin over
//            the 5e-4 f32-ordering-contested band).
//   PASS 2:  wave-cooperative exact fixup (BT gather + 6-lane HD panels
//            [384x5,128] folded left-to-right, bit-identical chain).
// Fallback (small ws / odd shapes): R12-certified fused bulk + W-col fixup.

typedef __bf16 bf16x8 __attribute__((ext_vector_type(8)));
typedef float f32x4 __attribute__((ext_vector_type(4)));

#define TAU 3e-3f

__device__ __forceinline__ float sgnf(float v) {
    return (v > 0.f) ? 1.f : ((v < 0.f) ? -1.f : 0.f);
}
__device__ __forceinline__ ushort f2bf(float x) {            // f32->bf16 RNE
    uint u = __float_as_uint(x);
    u += 0x7FFFu + ((u >> 16) & 1u);
    return (ushort)(u >> 16);
}
__device__ __forceinline__ float bf2f(ushort h) {
    return __uint_as_float(((uint)h) << 16);
}
__device__ __forceinline__ ushort sgnbf(float w) {           // sign as bf16
    return (w > 0.f) ? (ushort)0x3F80 : ((w < 0.f) ? (ushort)0xBF80 : (ushort)0);
}

// ---------------- PASS 0: fused pre-pass (conv rows + transpose tiles) -----
__global__ __launch_bounds__(256)
void pre_pass(const float* __restrict__ X, const float* __restrict__ W,
              ushort* __restrict__ A2, ushort* __restrict__ BT,
              uint* __restrict__ flags, int M, int K, int N)
{
    __shared__ float tile[64][65];
    const int b = blockIdx.x;

    if (b == 0 && threadIdx.x == 0) flags[0] = 0u;

    if (b < M) {
        const int m  = b;
        const int j8 = threadIdx.x * 8;
        if (j8 >= K) return;

        const float4 v0 = *(const float4*)&X[(size_t)m * K + j8];
        const float4 v1 = *(const float4*)&X[(size_t)m * K + j8 + 4];
        const float xs[8] = {v0.x, v0.y, v0.z, v0.w, v1.x, v1.y, v1.z, v1.w};

        ushort h1[8], h2[8];
        #pragma unroll
        for (int e = 0; e < 8; ++e) {
            h1[e] = f2bf(xs[e]);
            h2[e] = f2bf(xs[e] - bf2f(h1[e]));   // exact residual
        }
        uint4 p1, p2;
        p1.x = (uint)h1[0] | ((uint)h1[1] << 16);
        p1.y = (uint)h1[2] | ((uint)h1[3] << 16);
        p1.z = (uint)h1[4] | ((uint)h1[5] << 16);
        p1.w = (uint)h1[6] | ((uint)h1[7] << 16);
        p2.x = (uint)h2[0] | ((uint)h2[1] << 16);
        p2.y = (uint)h2[2] | ((uint)h2[3] << 16);
        p2.z = (uint)h2[4] | ((uint)h2[5] << 16);
        p2.w = (uint)h2[6] | ((uint)h2[7] << 16);

        ushort* row = A2 + (size_t)m * 2 * K;
        *(uint4*)(row + j8)     = p1;
        *(uint4*)(row + K + j8) = p2;
    } else {
        const int tb  = b - M;
        const int nbx = N >> 6;
        const int k0  = (tb / nbx) * 64;
        const int n0  = (tb % nbx) * 64;
        const int tr  = threadIdx.x >> 6;
        const int tc  = threadIdx.x & 63;

        #pragma unroll
        for (int h = 0; h < 16; ++h) {
            const int r = h * 4 + tr;
            tile[r][tc] = W[(size_t)(k0 + r) * N + n0 + tc];
        }
        __syncthreads();

        const int nr = threadIdx.x >> 2;
        const int kc = (threadIdx.x & 3) * 16;
        ushort sb[16];
        #pragma unroll
        for (int e = 0; e < 16; ++e) sb[e] = sgnbf(tile[kc + e][nr]);

        uint4 a2, b2;
        a2.x = (uint)sb[0]  | ((uint)sb[1]  << 16);
        a2.y = (uint)sb[2]  | ((uint)sb[3]  << 16);
        a2.z = (uint)sb[4]  | ((uint)sb[5]  << 16);
        a2.w = (uint)sb[6]  | ((uint)sb[7]  << 16);
        b2.x = (uint)sb[8]  | ((uint)sb[9]  << 16);
        b2.y = (uint)sb[10] | ((uint)sb[11] << 16);
        b2.z = (uint)sb[12] | ((uint)sb[13] << 16);
        b2.w = (uint)sb[14] | ((uint)sb[15] << 16);

        ushort* dst = BT + (size_t)(n0 + nr) * K + k0 + kc;
        *(uint4*)dst       = a2;
        *(uint4*)(dst + 8) = b2;
    }
}

// ---------------- PASS 1: 256x256, BK=32, reads-first pipelined COMPUTE ----
__global__ __launch_bounds__(512, 1)
void bulk_mfma_pl(const ushort* __restrict__ A2,   // [M][2K] bf16
                  const ushort* __restrict__ BT,   // [N][K]  bf16
                  float* __restrict__ O,
                  uint* __restrict__ flags, uint cap,
                  int M, int N, int K)
{
    __shared__ __align__(16) char lds[147456];  // 3 x {A 32KB | B 16KB}

    const int tid = threadIdx.x;
    const int l   = tid & 63;
    const int wid = tid >> 6;          // 0..7
    const int wm  = wid >> 2;          // 0..1
    const int wn  = wid & 3;           // 0..3
    const int lr  = l & 15;
    const int lk  = l >> 4;

    // bijective XCD swizzle (nwg % 8 == 0)
    const int nwg = gridDim.x;
    int wg = blockIdx.x;
    wg = (wg & 7) * (nwg >> 3) + (wg >> 3);
    const int nbx = N >> 8;
    const int m0 = (wg / nbx) << 8;
    const int n0 = (wg % nbx) << 8;

    const int NS = K >> 5;             // 32-real-k subtiles (64)
    const size_t rowA = (size_t)(2 * K) * 2;   // bytes per A2 row
    const size_t rowB = (size_t)K * 2;
    const char* A2b = (const char*)A2;
    const char* BTb = (const char*)BT;

    f32x4 acc[8][4];
    #pragma unroll
    for (int i = 0; i < 8; ++i)
        #pragma unroll
        for (int j = 0; j < 4; ++j)
            acc[i][j] = (f32x4){0.f, 0.f, 0.f, 0.f};

    // Stage subtile s into buffer buf: 6 gload_lds/thread.
    // LDS A: [256 rows][128B = {h1 64B | h2 64B}], XOR-swizzled (R16-proven);
    // LDS B: [128 pair-rows][128B = {n=2p | n=2p+1}], same swizzle.
    auto STAGE = [&](int buf, int s) {
        char* base = lds + buf * 49152;
        const size_t kOff = (size_t)s << 6;        // s*32 elems * 2B
        const int sub  = (((l & 7) ^ (l >> 3)) << 4);
        const int lrow = l >> 3;
        #pragma unroll
        for (int h = 0; h < 4; ++h) {              // A: 4 chunks/wave
            const int c   = wid * 4 + h;           // 0..31
            const int row = c * 8 + lrow;          // 0..255
            const size_t srcOff = kOff + (size_t)(sub & 63)
                                + ((sub & 64) ? (size_t)(2 * K) : 0);
            const char* srcA = A2b + (size_t)(m0 + row) * rowA + srcOff;
            __builtin_amdgcn_global_load_lds(
                (const __attribute__((address_space(1))) void*)srcA,
                (__attribute__((address_space(3))) void*)(base + c * 1024),
                16, 0, 0);
        }
        #pragma unroll
        for (int h = 0; h < 2; ++h) {              // B: 2 chunks/wave
            const int c = wid * 2 + h;             // 0..15
            const int p = c * 8 + lrow;            // 0..127
            const int nrow = 2 * p + ((sub >> 6) & 1);
            const char* srcB = BTb + (size_t)(n0 + nrow) * rowB
                             + kOff + (size_t)(sub & 63);
            __builtin_amdgcn_global_load_lds(
                (const __attribute__((address_space(1))) void*)srcB,
                (__attribute__((address_space(3))) void*)(base + 32768 + c * 1024),
                16, 0, 0);
        }
    };

    // Compute subtile: ALL 20 ds_reads first (bg, af plane1, af plane2),
    // then 64 MFMAs. Compiler emits counted lgkmcnt so plane-2 reads fly
    // under plane-1 MFMAs (within-wave LDS/MFMA overlap).
    auto COMPUTE = [&](int buf) {
        const char* sA = lds + buf * 49152;
        const char* sB = sA + 32768;
        bf16x8 bg[4];
        #pragma unroll
        for (int j = 0; j < 4; ++j) {
            const int r = wn * 64 + j * 16 + lr;
            const int p = r >> 1;
            const int byt = ((r & 1) * 64 + lk * 16) ^ ((p & 7) << 4);
            bg[j] = *(const bf16x8*)(sB + p * 128 + byt);
        }
        bf16x8 af1[8], af2[8];
        #pragma unroll
        for (int i = 0; i < 8; ++i) {
            const int row = wm * 128 + i * 16 + lr;
            const int swz = (row & 7) << 4;
            af1[i] = *(const bf16x8*)(sA + row * 128 + ((lk * 16) ^ swz));
            af2[i] = *(const bf16x8*)(sA + row * 128 + ((64 + lk * 16) ^ swz));
        }
        #pragma unroll
        for (int i = 0; i < 8; ++i)
            #pragma unroll
            for (int j = 0; j < 4; ++j)
                acc[i][j] = __builtin_amdgcn_mfma_f32_16x16x32_bf16(
                    af1[i], bg[j], acc[i][j], 0, 0, 0);
        #pragma unroll
        for (int i = 0; i < 8; ++i)
            #pragma unroll
            for (int j = 0; j < 4; ++j)
                acc[i][j] = __builtin_amdgcn_mfma_f32_16x16x32_bf16(
                    af2[i], bg[j], acc[i][j], 0, 0, 0);
    };

    // prologue: 3 subtiles in flight (18 loads/thread)
    STAGE(0, 0);
    STAGE(1, 1);
    STAGE(2, 2);

    for (int s = 0; s < NS; ++s) {
        const int nw = ((NS < s + 3) ? NS : (s + 3)) - (s + 1);
        if (nw == 2)      asm volatile("s_waitcnt vmcnt(12)" ::: "memory");
        else if (nw == 1) asm volatile("s_waitcnt vmcnt(6)"  ::: "memory");
        else              asm volatile("s_waitcnt vmcnt(0)"  ::: "memory");
        __builtin_amdgcn_s_barrier();
        __builtin_amdgcn_sched_barrier(0);
        COMPUTE(s % 3);
        __builtin_amdgcn_s_barrier();
        __builtin_amdgcn_sched_barrier(0);
        if (s + 3 < NS) STAGE(s % 3, s + 3);   // refill just-freed buffer
    }

    // epilogue: sign + borderline flagging (C/D: col=lane&15, row=lk*4+q)
    #pragma unroll
    for (int i = 0; i < 8; ++i) {
        #pragma unroll
        for (int j = 0; j < 4; ++j) {
            #pragma unroll
            for (int q = 0; q < 4; ++q) {
                const int m = m0 + wm * 128 + i * 16 + lk * 4 + q;
                const int n = n0 + wn * 64 + j * 16 + lr;
                const float d = acc[i][j][q];
                const size_t oi = (size_t)m * N + n;
                O[oi] = sgnf(d);
                if (fabsf(d) < TAU) {
                    const uint pos = atomicAdd(flags, 1u);
                    if (pos < cap) flags[1 + pos] = (uint)oi;
                }
            }
        }
    }
}

// ---------------- FALLBACK bulk (R12-certified, fused conversion) ----------
__global__ __launch_bounds__(256, 2)
void bulk_mfma_fb(const float* __restrict__ X, const float* __restrict__ W,
                  float* __restrict__ O, uint* __restrict__ flags,
                  uint cap, int M, int N, int K)
{
    __shared__ __align__(16) char sA[128 * 128];
    __shared__ __align__(16) char sB[128 * 128];

    const int tid = threadIdx.x;
    const int l   = tid & 63;
    const int w   = tid >> 6;
    const int wr  = w >> 1, wc = w & 1;
    const int lr  = l & 15;
    const int lk  = l >> 4;

    const int m0 = blockIdx.y * 128;
    const int n0 = blockIdx.x * 128;

    f32x4 acc[4][4];
    #pragma unroll
    for (int i = 0; i < 4; ++i)
        #pragma unroll
        for (int j = 0; j < 4; ++j)
            acc[i][j] = (f32x4){0.f, 0.f, 0.f, 0.f};

    const int NT = K / 64;

    for (int kt = 0; kt < 2 * NT; ++kt) {
        const int plane = (kt >= NT);
        const int kr0 = (plane ? (kt - NT) : kt) * 64;

        #pragma unroll
        for (int h = 0; h < 4; ++h) {
            const int idx = tid + 256 * h;
            const int r   = idx >> 3;
            const int c8  = (idx & 7) * 8;
            const float* xp = &X[(size_t)(m0 + r) * K + kr0 + c8];
            const float4 v0 = *(const float4*)xp;
            const float4 v1 = *(const float4*)(xp + 4);
            const float xs[8] = {v0.x, v0.y, v0.z, v0.w, v1.x, v1.y, v1.z, v1.w};
            ushort hb[8];
            if (!plane) {
                #pragma unroll
                for (int e = 0; e < 8; ++e) hb[e] = f2bf(xs[e]);
            } else {
                #pragma unroll
                for (int e = 0; e < 8; ++e) {
                    const ushort h1 = f2bf(xs[e]);
                    hb[e] = f2bf(xs[e] - bf2f(h1));
                }
            }
            uint4 pk;
            pk.x = (uint)hb[0] | ((uint)hb[1] << 16);
            pk.y = (uint)hb[2] | ((uint)hb[3] << 16);
            pk.z = (uint)hb[4] | ((uint)hb[5] << 16);
            pk.w = (uint)hb[6] | ((uint)hb[7] << 16);
            *(uint4*)(sA + r * 128 + ((c8 * 2) ^ ((r & 7) << 4))) = pk;
        }
        {
            const int ko = (tid >> 5) * 8;
            const int n4 = (tid & 31) * 4;
            float4 rv[8];
            #pragma unroll
            for (int j = 0; j < 8; ++j)
                rv[j] = *(const float4*)&W[(size_t)(kr0 + ko + j) * N + n0 + n4];
            #pragma unroll
            for (int c = 0; c < 4; ++c) {
                ushort sb[8];
                #pragma unroll
                for (int j = 0; j < 8; ++j)
                    sb[j] = sgnbf(((const float*)&rv[j])[c]);
                uint4 pk;
                pk.x = (uint)sb[0] | ((uint)sb[1] << 16);
                pk.y = (uint)sb[2] | ((uint)sb[3] << 16);
                pk.z = (uint)sb[4] | ((uint)sb[5] << 16);
                pk.w = (uint)sb[6] | ((uint)sb[7] << 16);
                const int row = n4 + c;
                *(uint4*)(sB + row * 128 + ((ko * 2) ^ ((row & 7) << 4))) = pk;
            }
        }
        __syncthreads();

        #pragma unroll
        for (int kk = 0; kk < 2; ++kk) {
            const int kb = kk * 64 + lk * 16;
            bf16x8 af[4], bg[4];
            #pragma unroll
            for (int i = 0; i < 4; ++i) {
                const int row = wr * 64 + i * 16 + lr;
                af[i] = *(const bf16x8*)(sA + row * 128 + (kb ^ ((row & 7) << 4)));
            }
            #pragma unroll
            for (int j = 0; j < 4; ++j) {
                const int row = wc * 64 + j * 16 + lr;
                bg[j] = *(const bf16x8*)(sB + row * 128 + (kb ^ ((row & 7) << 4)));
            }
            #pragma unroll
            for (int i = 0; i < 4; ++i)
                #pragma unroll
                for (int j = 0; j < 4; ++j)
                    acc[i][j] = __builtin_amdgcn_mfma_f32_16x16x32_bf16(
                        af[i], bg[j], acc[i][j], 0, 0, 0);
        }
        __syncthreads();
    }

    #pragma unroll
    for (int i = 0; i < 4; ++i) {
        #pragma unroll
        for (int j = 0; j < 4; ++j) {
            #pragma unroll
            for (int q = 0; q < 4; ++q) {
                const int m = m0 + wr * 64 + i * 16 + lk * 4 + q;
                const int n = n0 + wc * 64 + j * 16 + lr;
                const float d = acc[i][j][q];
                const size_t oi = (size_t)m * N + n;
                O[oi] = sgnf(d);
                if (fabsf(d) < TAU) {
                    const uint pos = atomicAdd(flags, 1u);
                    if (pos < cap) flags[1 + pos] = (uint)oi;
                }
            }
        }
    }
}

// ---------------- PASS 2: fixup, BT gather + 6-lane panel-parallel chain ---
__global__ __launch_bounds__(64)
void fixup_exact_bt(const float* __restrict__ X, const ushort* __restrict__ BT,
                    float* __restrict__ O, const uint* __restrict__ flags,
                    uint cap, int K, int N)
{
    __shared__ float p[2048];

    uint count = flags[0];
    if (count > cap) count = cap;

    for (uint t = blockIdx.x; t < count; t += gridDim.x) {
        const uint idx = flags[1 + t];
        const int n = (int)(idx % (uint)N);
        const float* xrow = X + (size_t)(idx / (uint)N) * K;
        const ushort* brow = BT + (size_t)n * K;

        for (int k4 = threadIdx.x * 4; k4 < K; k4 += 256) {
            const float4 xv = *(const float4*)&xrow[k4];
            const ushort4 bv = *(const ushort4*)&brow[k4];
            float4 pr;
            pr.x = xv.x * bf2f(bv.x);
            pr.y = xv.y * bf2f(bv.y);
            pr.z = xv.z * bf2f(bv.z);
            pr.w = xv.w * bf2f(bv.w);
            *(float4*)&p[k4] = pr;       // exact +-x products
        }
        __syncthreads();

        // HD panels [384x5,128]: panel t on lane t (internally sequential),
        // folded left-to-right (exact order).
        float partial = 0.f;
        const int ls = (int)threadIdx.x * 384;
        if (ls < K) {
            const int ke = (ls + 384 < K) ? (ls + 384) : K;
            for (int k = ls; k < ke; ++k) partial += p[k];
        }
        float sum = 0.f;
        #pragma unroll
        for (int q = 0; q < 6; ++q) sum += __shfl(partial, q);
        if (threadIdx.x == 0) O[idx] = sgnf(sum);
        __syncthreads();
    }
}

// ---------------- fallback fixup (reads W columns) ----------------
__global__ __launch_bounds__(64)
void fixup_exact_wave(const float* __restrict__ X, const float* __restrict__ W,
                      float* __restrict__ O, const uint* __restrict__ flags,
                      uint cap, int K, int N)
{
    __shared__ float p[2048];

    uint count = flags[0];
    if (count > cap) count = cap;

    for (uint t = blockIdx.x; t < count; t += gridDim.x) {
        const uint idx = flags[1 + t];
        const int n = (int)(idx % (uint)N);
        const float* xrow = X + (size_t)(idx / (uint)N) * K;
        const float* wcol = W + n;

        if (K <= 2048) {
            for (int k = threadIdx.x; k < K; k += 64)
                p[k] = xrow[k] * sgnf(wcol[(size_t)k * N]);
            __syncthreads();
            if (threadIdx.x == 0) {
                float sum = 0.f;
                int ls = 0;
                while (ls < K) {
                    const int ke = (ls + 384 < K) ? (ls + 384) : K;
                    float part = 0.f;
                    for (int k = ls; k < ke; ++k) part += p[k];
                    sum += part;
                    ls = ke;
                }
                O[idx] = sgnf(sum);
            }
            __syncthreads();
        } else if (threadIdx.x == 0) {
            float sum = 0.f;
            int ls = 0;
            while (ls < K) {
                const int ke = (ls + 384 < K) ? (ls + 384) : K;
                float part = 0.f;
                for (int k = ls; k < ke; ++k)
                    part = fmaf(xrow[k], sgnf(wcol[(size_t)k * N]), part);
                sum += part;
                ls = ke;
            }
            O[idx] = sgnf(sum);
        }
    }
}

extern "C" void kernel_launch(void* const* d_in, const int* in_sizes, int n_in,
                              void* d_out, int out_size, void* d_ws, size_t ws_size,
                              hipStream_t stream) {
    // order-robust input binding (x = larger buffer)
    const float* X;
    const float* W;
    long long wsize;
    if ((long long)in_sizes[0] >= (long long)in_sizes[1]) {
        X = (const float*)d_in[0];
        W = (const float*)d_in[1]; wsize = in_sizes[1];
    } else {
        X = (const float*)d_in[1];
        W = (const float*)d_in[0]; wsize = in_sizes[0];
    }
    float* O = (float*)d_out;

    int K = 1;
    while ((long long)K * K < wsize) ++K;        // K = 2048
    const int N = K;
    const int M = (int)((long long)out_size / N);

    const size_t A2_BYTES = (size_t)M * 2 * K * 2;   // 64 MB
    const size_t BT_BYTES = (size_t)N * K * 2;       // 8 MB
    const size_t FLAG_OFF = A2_BYTES + BT_BYTES;
    const bool big_ws = (ws_size >= FLAG_OFF + (1u << 16)) &&
                        (M % 256 == 0) && (N % 256 == 0) &&
                        (K % 64 == 0) && (K >= 256) && (K <= 2048);

    if (big_ws) {
        ushort* A2 = (ushort*)d_ws;
        ushort* BT = (ushort*)((char*)d_ws + A2_BYTES);
        uint* flags = (uint*)((char*)d_ws + FLAG_OFF);
        unsigned long long c = (unsigned long long)((ws_size - FLAG_OFF) / 4) - 1ull;
        const uint cap = (uint)((c > 0x00FFFFFFull) ? 0x00FFFFFFull : c);

        const int pre_grid = M + (N / 64) * (K / 64);
        pre_pass<<<pre_grid, 256, 0, stream>>>(X, W, A2, BT, flags, M, K, N);
        const int nwg = (N / 256) * (M / 256);       // 256, % 8 == 0
        bulk_mfma_pl<<<nwg, 512, 0, stream>>>(A2, BT, O, flags, cap, M, N, K);
        fixup_exact_bt<<<2048, 64, 0, stream>>>(X, BT, O, flags, cap, K, N);
    } else {
        uint* flags = (uint*)d_ws;
        uint cap = 0;
        if (ws_size >= 8) {
            unsigned long long c = (unsigned long long)(ws_size / 4) - 1ull;
            cap = (uint)((c > 0x00FFFFFFull) ? 0x00FFFFFFull : c);
        }
        hipMemsetAsync(d_ws, 0, 4, stream);
        dim3 grid(N / 128, M / 128);
        bulk_mfma_fb<<<grid, 256, 0, stream>>>(X, W, O, flags, cap, M, N, K);
        fixup_exact_wave<<<2048, 64, 0, stream>>>(X, W, O, flags, cap, K, N);
    }
}